// Round 17
// baseline (416.439 us; speedup 1.0000x reference)
//
#include <hip/hip_runtime.h>
#include <hip/hip_fp16.h>
#include <math.h>

#define NN 50000
#define EE 800000
#define DFi 8
#define DHc 32
#define Hh 4
#define HCc 128
#define DEe 4
#define DDd 256
#define DOo 4
#define NBK 196   // (NN+255)/256

// ---------------- edge-index dtype detect + convert (+count +rank fused) ----------------
__global__ void detect_kernel(const unsigned int* __restrict__ w, int nwords, int* __restrict__ flag) {
    unsigned int acc = 0;
    for (int i = 2 * threadIdx.x + 1; i < nwords; i += 512) acc |= w[i];
    if (acc) atomicOr(flag, 1);
}

__global__ void convert_count_kernel(const void* __restrict__ buf, const int* __restrict__ flag,
                                     int* __restrict__ EI, int* __restrict__ counts,
                                     int* __restrict__ rnk) {
    int i = blockIdx.x * 256 + threadIdx.x;
    if (i >= 2 * EE) return;
    int v = (*flag) ? ((const int*)buf)[i] : (int)(((const long long*)buf)[i]);
    EI[i] = v;
    if (i >= EE) rnk[i - EE] = atomicAdd(&counts[v], 1);
}

// ---------------- CSR build ----------------
__global__ void scanA_kernel(const int* __restrict__ counts, int* __restrict__ roff,
                             int* __restrict__ bsum, int M) {
    __shared__ int sd[256];
    int t = threadIdx.x;
    int idx = blockIdx.x * 256 + t;
    int v = (idx < M) ? counts[idx] : 0;
    sd[t] = v;
    __syncthreads();
    for (int off = 1; off < 256; off <<= 1) {
        int x = (t >= off) ? sd[t - off] : 0;
        __syncthreads();
        sd[t] += x;
        __syncthreads();
    }
    if (idx < M) roff[idx] = sd[t] - v;      // exclusive
    if (t == 255) bsum[blockIdx.x] = sd[255];
}

__global__ void scanB_kernel(const int* __restrict__ bsum, int* __restrict__ boff, int nb) {
    __shared__ int sd[256];
    int t = threadIdx.x;
    int v = (t < nb) ? bsum[t] : 0;
    sd[t] = v;
    __syncthreads();
    for (int off = 1; off < 256; off <<= 1) {
        int x = (t >= off) ? sd[t - off] : 0;
        __syncthreads();
        sd[t] += x;
        __syncthreads();
    }
    boff[t] = sd[t] - v;                     // exclusive
}

__global__ void scanC_kernel(int* __restrict__ roff, const int* __restrict__ boff, int M) {
    int idx = blockIdx.x * 256 + threadIdx.x;
    if (idx < M) roff[idx] += boff[idx >> 8];
}

// no atomics: rank was captured during the count pass
__global__ void fill_kernel(const int* __restrict__ EI, const int* __restrict__ roff,
                            const int* __restrict__ rnk, long long* __restrict__ ce) {
    int e = blockIdx.x * 256 + threadIdx.x;
    if (e >= EE) return;
    int d = EI[EE + e];
    int s = EI[e];
    ce[roff[d] + rnk[e]] = ((long long)e << 32) | (unsigned int)s;
}

// sort each segment by eid (deterministic) AND materialize CSR-ordered col[] + fp16 EAc[].
__global__ __launch_bounds__(256) void sortw_kernel(const int* __restrict__ roff,
                                                    long long* __restrict__ ce,
                                                    const float4* __restrict__ EA4,
                                                    int* __restrict__ col,
                                                    __half* __restrict__ EAc) {
    const int n = blockIdx.x * 4 + (threadIdx.x >> 6);
    if (n >= NN) return;
    const int lane = threadIdx.x & 63;
    const int a = roff[n];
    const int d = roff[n + 1] - a;
    if (d <= 0) return;
    if (d <= 64) {
        int srcv = 0;
        unsigned key = 0xFFFFFFFFu;
        if (lane < d) {
            long long v = ce[a + lane];
            srcv = (int)(v & 0xffffffffLL);
            unsigned eid = (unsigned)(v >> 32);
            key = (eid << 6) | (unsigned)lane;
        }
#pragma unroll
        for (int k = 2; k <= 64; k <<= 1) {
#pragma unroll
            for (int j = k >> 1; j > 0; j >>= 1) {
                unsigned o = (unsigned)__shfl_xor((int)key, j);
                bool up = ((lane & k) == 0);
                bool lower = ((lane & j) == 0);
                unsigned mn = o < key ? o : key;
                unsigned mx = o < key ? key : o;
                key = (lower == up) ? mn : mx;
            }
        }
        if (lane < d) {
            int ol = (int)(key & 63u);
            int src = __shfl(srcv, ol);
            unsigned eid = key >> 6;
            col[a + lane] = src;
            float4 at = EA4[eid];
            __half2 lo = __floats2half2_rn(at.x, at.y);
            __half2 hi = __floats2half2_rn(at.z, at.w);
            uint2 pk;
            pk.x = *reinterpret_cast<unsigned int*>(&lo);
            pk.y = *reinterpret_cast<unsigned int*>(&hi);
            reinterpret_cast<uint2*>(EAc)[a + lane] = pk;
        }
    } else if (lane == 0) {
        for (int i2 = a + 1; i2 < a + d; i2++) {
            long long kk = ce[i2];
            int j2 = i2 - 1;
            while (j2 >= a && ce[j2] > kk) { ce[j2 + 1] = ce[j2]; j2--; }
            ce[j2 + 1] = kk;
        }
        for (int k = 0; k < d; k++) {
            long long key = ce[a + k];
            int src = (int)(key & 0xffffffffLL);
            int eid = (int)(key >> 32);
            col[a + k] = src;
            float4 at = EA4[eid];
            __half2 lo = __floats2half2_rn(at.x, at.y);
            __half2 hi = __floats2half2_rn(at.z, at.w);
            uint2 pk;
            pk.x = *reinterpret_cast<unsigned int*>(&lo);
            pk.y = *reinterpret_cast<unsigned int*>(&hi);
            reinterpret_cast<uint2*>(EAc)[a + k] = pk;
        }
    }
}

// ---------------- degree-sorted node permutation: block-local counting sort (LDS only) ------
__global__ __launch_bounds__(256) void bhist_kernel(const int* __restrict__ roff, int* __restrict__ gbh) {
    __shared__ int hist[256];
    int t = threadIdx.x;
    hist[t] = 0;
    __syncthreads();
    int n = blockIdx.x * 256 + t;
    if (n < NN) {
        int d = roff[n + 1] - roff[n];
        atomicAdd(&hist[d < 255 ? d : 255], 1);
    }
    __syncthreads();
    gbh[t * NBK + blockIdx.x] = hist[t];
}

__global__ __launch_bounds__(256) void bscan_kernel(int* __restrict__ gbh) {
    __shared__ int sd[256];
    int bin = threadIdx.x;
    int s = 0;
    for (int b = 0; b < NBK; b++) { int v = gbh[bin * NBK + b]; gbh[bin * NBK + b] = s; s += v; }
    int r = 255 - bin;                 // reversed: heavy bins first (LPT)
    sd[r] = s;
    __syncthreads();
    for (int off = 1; off < 256; off <<= 1) {
        int x = (r >= off) ? sd[r - off] : 0;
        __syncthreads();
        sd[r] += x;
        __syncthreads();
    }
    int base = sd[r] - s;
    for (int b = 0; b < NBK; b++) gbh[bin * NBK + b] += base;
}

__global__ __launch_bounds__(256) void bscatter_kernel(const int* __restrict__ roff,
                                                       const int* __restrict__ gbh,
                                                       int* __restrict__ perm) {
    __shared__ int hist[256];
    int t = threadIdx.x;
    hist[t] = 0;
    __syncthreads();
    int n = blockIdx.x * 256 + t;
    if (n < NN) {
        int d = roff[n + 1] - roff[n];
        int bin = d < 255 ? d : 255;
        int lr = atomicAdd(&hist[bin], 1);
        perm[gbh[bin * NBK + blockIdx.x] + lr] = n;
    }
}

// ---------------- node transform: XLh/XRh = fp16 transforms, per-head norms (f32) ----------
template <int IN>
__global__ __launch_bounds__(128) void transform_kernel(
    const float* __restrict__ Xin, const float* __restrict__ Wl, const float* __restrict__ bl,
    const float* __restrict__ Wr, const float* __restrict__ br,
    __half* __restrict__ XLh, __half* __restrict__ XRh,
    float* __restrict__ NLn, float* __restrict__ NRn) {
    const int t = threadIdx.x;
    float wl[IN], wr[IN];
#pragma unroll
    for (int k = 0; k < IN; k++) { wl[k] = Wl[k * HCc + t]; wr[k] = Wr[k * HCc + t]; }
    const float blv = bl[t], brv = br[t];
    __shared__ float xst[16][IN];
    const int nbeg = blockIdx.x * 16;
    for (int idx = t; idx < 16 * IN; idx += 128) {
        int r = idx / IN, cc = idx % IN;
        int n = nbeg + r;
        xst[r][cc] = (n < NN) ? Xin[n * IN + cc] : 0.f;
    }
    __syncthreads();
#pragma unroll 4
    for (int r = 0; r < 16; ++r) {
        int n = nbeg + r;
        if (n >= NN) break;
        float al = blv, ar = brv;
#pragma unroll
        for (int k = 0; k < IN; k++) { float xv = xst[r][k]; al = fmaf(xv, wl[k], al); ar = fmaf(xv, wr[k], ar); }
        XLh[n * HCc + t] = __float2half(al);
        XRh[n * HCc + t] = __float2half(ar);
        float sl = al * al, sr = ar * ar;
#pragma unroll
        for (int msk = 1; msk < 32; msk <<= 1) { sl += __shfl_xor(sl, msk); sr += __shfl_xor(sr, msk); }
        if ((t & 31) == 0) { NLn[n * 4 + (t >> 5)] = sqrtf(sl); NRn[n * 4 + (t >> 5)] = sqrtf(sr); }
    }
}

__device__ inline float4 h8tof4(unsigned int a, unsigned int b) {
    __half2 p0 = *reinterpret_cast<const __half2*>(&a);
    __half2 p1 = *reinterpret_cast<const __half2*>(&b);
    float2 lo = __half22float2(p0), hi = __half22float2(p1);
    return make_float4(lo.x, lo.y, hi.x, hi.y);
}

// ---------------- fused per-node GAT layer: 2 nodes per wave (32 lanes/node) ------------
// 32-lane group g2 = lane>>5 owns ONE node; lane c = lane&31 owns fp16 channels 4c..4c+3
// (head = c>>3). Thin per-lane state (VGPR ~48) -> high wave residency -> more gather MLP.
__global__ __launch_bounds__(256) void gat_kernel(
    const __half* __restrict__ XLh, const __half* __restrict__ XRh,
    const float* __restrict__ NLn, const float* __restrict__ NRn,
    const int* __restrict__ roff, const int* __restrict__ col,
    const __half* __restrict__ EAc, const int* __restrict__ perm,
    const float* __restrict__ We,
    const float* __restrict__ att, const float* __restrict__ bo,
    float* __restrict__ Hout) {
    const int lane = threadIdx.x & 63;
    const int c = lane & 31;
    const int g2 = lane >> 5;
    const int h = c >> 3;
    const int slot = blockIdx.x * 8 + (threadIdx.x >> 6) * 2 + g2;
    if (slot >= NN) return;
    const int i = perm[slot];

    const uint2*  XLu2 = reinterpret_cast<const uint2*>(XLh);   // 8B = 4 halves per lane
    const uint2*  XRu2 = reinterpret_cast<const uint2*>(XRh);
    const uint2*  EAu2 = reinterpret_cast<const uint2*>(EAc);
    const float4* NL4 = reinterpret_cast<const float4*>(NLn);
    const float4* We4 = reinterpret_cast<const float4*>(We);
    const float4* at4 = reinterpret_cast<const float4*>(att);
    const float4* bo4 = reinterpret_cast<const float4*>(bo);
    float4* Ho4 = reinterpret_cast<float4*>(Hout);

    const int base = roff[i];
    const int deg = roff[i + 1] - base;

    if (deg == 0) {
        if (c < 8) {
            float4 b = bo4[c];
            float4 r;
            r.x = b.x > 0.f ? b.x : 0.01f * b.x;
            r.y = b.y > 0.f ? b.y : 0.01f * b.y;
            r.z = b.z > 0.f ? b.z : 0.01f * b.z;
            r.w = b.w > 0.f ? b.w : 0.01f * b.w;
            Ho4[i * 8 + c] = r;
        }
        return;
    }

    // per-lane constants (4 channels)
    const float4 w0 = We4[c], w1 = We4[32 + c], w2 = We4[64 + c], w3 = We4[96 + c];
    const float4 at = at4[c];
    uint2 xiu = XRu2[i * 32 + c];
    const float4 xi = h8tof4(xiu.x, xiu.y);

    float srun = 0.f;
    float4 acc = make_float4(0.f, 0.f, 0.f, 0.f);

#define ISSUE(X_, E_, K)                                                          \
    {                                                                             \
        int kc = ((K) < deg) ? (K) : 0;                                           \
        int jx = col[base + kc];                                                  \
        X_ = XLu2[jx * 32 + c];                                                   \
        E_ = EAu2[base + kc];                                                     \
    }
    // early-issue 6 slots before the norm phase
    uint2 xA, xB, xC, xD, xE, xF;
    uint2 eA, eB, eC, eD, eE, eF;
    ISSUE(xA, eA, 0); ISSUE(xB, eB, 1); ISSUE(xC, eC, 2);
    ISSUE(xD, eD, 3); ISSUE(xE, eE, 4); ISSUE(xF, eF, 5);

    // phase 1: Lipschitz max of in-neighbor norms (strided over 32 lanes; norms >= 0)
    float4 mx = make_float4(0.f, 0.f, 0.f, 0.f);
    for (int k = c; k < deg; k += 32) {
        int j = col[base + k];
        float4 nj = NL4[j];
        mx.x = fmaxf(mx.x, nj.x); mx.y = fmaxf(mx.y, nj.y);
        mx.z = fmaxf(mx.z, nj.z); mx.w = fmaxf(mx.w, nj.w);
    }
#pragma unroll
    for (int msk = 1; msk < 32; msk <<= 1) {
        mx.x = fmaxf(mx.x, __shfl_xor(mx.x, msk));
        mx.y = fmaxf(mx.y, __shfl_xor(mx.y, msk));
        mx.z = fmaxf(mx.z, __shfl_xor(mx.z, msk));
        mx.w = fmaxf(mx.w, __shfl_xor(mx.w, msk));
    }
    float mxh = (h == 0) ? mx.x : (h == 1) ? mx.y : (h == 2) ? mx.z : mx.w;
    const float invD = 1.0f / (4.0f * (NRn[i * 4 + h] + mxh) + 1e-12f);

#define BODY(X_, E_, K)                                                           \
    {                                                                             \
        float4 a4 = h8tof4((E_).x, (E_).y);                                       \
        float4 xj = h8tof4((X_).x, (X_).y);                                       \
        float e0 = a4.x * w0.x; e0 = fmaf(a4.y, w1.x, e0);                        \
        e0 = fmaf(a4.z, w2.x, e0); e0 = fmaf(a4.w, w3.x, e0);                     \
        float e1 = a4.x * w0.y; e1 = fmaf(a4.y, w1.y, e1);                        \
        e1 = fmaf(a4.z, w2.y, e1); e1 = fmaf(a4.w, w3.y, e1);                     \
        float e2 = a4.x * w0.z; e2 = fmaf(a4.y, w1.z, e2);                        \
        e2 = fmaf(a4.z, w2.z, e2); e2 = fmaf(a4.w, w3.z, e2);                     \
        float e3 = a4.x * w0.w; e3 = fmaf(a4.y, w1.w, e3);                        \
        e3 = fmaf(a4.z, w2.w, e3); e3 = fmaf(a4.w, w3.w, e3);                     \
        float s0 = xi.x + xj.x + e0; s0 = s0 > 0.f ? s0 : 0.2f * s0;              \
        float s1 = xi.y + xj.y + e1; s1 = s1 > 0.f ? s1 : 0.2f * s1;              \
        float s2 = xi.z + xj.z + e2; s2 = s2 > 0.f ? s2 : 0.2f * s2;              \
        float s3 = xi.w + xj.w + e3; s3 = s3 > 0.f ? s3 : 0.2f * s3;              \
        float pp = s0 * at.x; pp = fmaf(s1, at.y, pp);                            \
        pp = fmaf(s2, at.z, pp); pp = fmaf(s3, at.w, pp);                         \
        pp += __shfl_xor(pp, 1); pp += __shfl_xor(pp, 2);                         \
        pp += __shfl_xor(pp, 4);                                                  \
        float z = __expf(fminf(pp * invD, 60.f));                                 \
        z = ((K) < deg) ? z : 0.f;                                                \
        srun += z;                                                                \
        acc.x = fmaf(z, xj.x, acc.x);                                             \
        acc.y = fmaf(z, xj.y, acc.y);                                             \
        acc.z = fmaf(z, xj.z, acc.z);                                             \
        acc.w = fmaf(z, xj.w, acc.w);                                             \
    }

    for (int k = 0; k < deg; k += 3) {
        uint2 nxD, nxE, nxF;
        uint2 neD, neE, neF;
        ISSUE(nxD, neD, k + 6);
        ISSUE(nxE, neE, k + 7);
        ISSUE(nxF, neF, k + 8);
        BODY(xA, eA, k);
        if (k + 1 < deg) BODY(xB, eB, k + 1);
        if (k + 2 < deg) BODY(xC, eC, k + 2);
        xA = xD; eA = eD; xB = xE; eB = eE; xC = xF; eC = eF;
        xD = nxD; eD = neD; xE = nxE; eE = neE; xF = nxF; eF = neF;
    }
#undef BODY
#undef ISSUE

    float inv = 1.0f / (srun + 1e-16f);
    float a0 = acc.x * inv, a1 = acc.y * inv, a2 = acc.z * inv, a3 = acc.w * inv;
    // head mean: sum over c bits 3,4; result at c<8
    a0 += __shfl_xor(a0, 8); a0 += __shfl_xor(a0, 16);
    a1 += __shfl_xor(a1, 8); a1 += __shfl_xor(a1, 16);
    a2 += __shfl_xor(a2, 8); a2 += __shfl_xor(a2, 16);
    a3 += __shfl_xor(a3, 8); a3 += __shfl_xor(a3, 16);

    if (c < 8) {
        float4 b = bo4[c];
        float4 r;
        r.x = fmaf(0.25f, a0, b.x); r.x = r.x > 0.f ? r.x : 0.01f * r.x;
        r.y = fmaf(0.25f, a1, b.y); r.y = r.y > 0.f ? r.y : 0.01f * r.y;
        r.z = fmaf(0.25f, a2, b.z); r.z = r.z > 0.f ? r.z : 0.01f * r.z;
        r.w = fmaf(0.25f, a3, b.w); r.w = r.w > 0.f ? r.w : 0.01f * r.w;
        Ho4[i * 8 + c] = r;
    }
}

// ---------------- MLP head ----------------
__global__ __launch_bounds__(256) void mlp_kernel(
    const float* __restrict__ Hin, const float* __restrict__ Wd1, const float* __restrict__ bd1,
    const float* __restrict__ Wd2, const float* __restrict__ bd2, float* __restrict__ out) {
    const int lane = threadIdx.x & 63;
    const int chunk = __builtin_amdgcn_readfirstlane(threadIdx.x >> 6);
    const int nb = blockIdx.x * 64;
    int node = nb + lane;
    int nclamp = node < NN ? node : NN - 1;

    float h[32];
    const float4* H4 = reinterpret_cast<const float4*>(Hin);
#pragma unroll
    for (int r = 0; r < 8; ++r) {
        float4 t = H4[nclamp * 8 + r];
        h[4 * r] = t.x; h[4 * r + 1] = t.y; h[4 * r + 2] = t.z; h[4 * r + 3] = t.w;
    }

    float o0 = 0.f, o1 = 0.f, o2 = 0.f, o3 = 0.f;
    const int dbase = chunk * 64;
    for (int t = 0; t < 4; ++t) {
        float acc[16];
#pragma unroll
        for (int j = 0; j < 16; ++j) acc[j] = bd1[dbase + t * 16 + j];
#pragma unroll 8
        for (int k = 0; k < 32; ++k) {
            const float* wr = Wd1 + k * DDd + dbase + t * 16;
#pragma unroll
            for (int j = 0; j < 16; ++j) acc[j] = fmaf(h[k], wr[j], acc[j]);
        }
#pragma unroll
        for (int j = 0; j < 16; ++j) {
            float hd = acc[j];
            hd = hd > 0.f ? hd : 0.01f * hd;
            int d = dbase + t * 16 + j;
            o0 = fmaf(hd, Wd2[d * 4 + 0], o0);
            o1 = fmaf(hd, Wd2[d * 4 + 1], o1);
            o2 = fmaf(hd, Wd2[d * 4 + 2], o2);
            o3 = fmaf(hd, Wd2[d * 4 + 3], o3);
        }
    }

    __shared__ float4 red[4][64];
    red[chunk][lane] = make_float4(o0, o1, o2, o3);
    __syncthreads();
    if (threadIdx.x < 64 && nb + (int)threadIdx.x < NN) {
        float4 r0 = red[0][threadIdx.x], r1 = red[1][threadIdx.x];
        float4 r2 = red[2][threadIdx.x], r3 = red[3][threadIdx.x];
        float4 o;
        o.x = r0.x + r1.x + r2.x + r3.x + bd2[0];
        o.y = r0.y + r1.y + r2.y + r3.y + bd2[1];
        o.z = r0.z + r1.z + r2.z + r3.z + bd2[2];
        o.w = r0.w + r1.w + r2.w + r3.w + bd2[3];
        reinterpret_cast<float4*>(out)[nb + threadIdx.x] = o;
    }
}

extern "C" void kernel_launch(void* const* d_in, const int* in_sizes, int n_in,
                              void* d_out, int out_size, void* d_ws, size_t ws_size,
                              hipStream_t stream) {
    const float* x    = (const float*)d_in[0];
    const void*  eraw = d_in[1];
    const float* ea   = (const float*)d_in[2];
    const float* Wl0  = (const float*)d_in[3];
    const float* bl0  = (const float*)d_in[4];
    const float* Wr0  = (const float*)d_in[5];
    const float* br0  = (const float*)d_in[6];
    const float* We0  = (const float*)d_in[7];
    const float* att0 = (const float*)d_in[8];
    const float* bo0  = (const float*)d_in[9];
    const float* Wl   = (const float*)d_in[10];
    const float* bl   = (const float*)d_in[11];
    const float* Wr   = (const float*)d_in[12];
    const float* br   = (const float*)d_in[13];
    const float* We   = (const float*)d_in[14];
    const float* att  = (const float*)d_in[15];
    const float* bo   = (const float*)d_in[16];
    const float* Wd1  = (const float*)d_in[17];
    const float* bd1  = (const float*)d_in[18];
    const float* Wd2  = (const float*)d_in[19];
    const float* bd2  = (const float*)d_in[20];
    float* out = (float*)d_out;

    char* p = (char*)d_ws;
    auto alloc = [&](size_t bytes) { void* r = (void*)p; p += (bytes + 255) & ~(size_t)255; return r; };
    int*       EI     = (int*)alloc((size_t)2 * EE * 4);
    int*       counts = (int*)alloc((size_t)(NN + 1) * 4);
    int*       roff   = (int*)alloc((size_t)(NN + 1) * 4);
    int*       bsum   = (int*)alloc(256 * 4);
    int*       boff   = (int*)alloc(256 * 4);
    int*       rnk    = (int*)alloc((size_t)EE * 4);
    long long* ce     = (long long*)alloc((size_t)EE * 8);
    int*       col    = (int*)alloc((size_t)EE * 4);
    int*       flag   = (int*)alloc(256);
    int*       gbh    = (int*)alloc((size_t)256 * NBK * 4);
    int*       perm   = (int*)alloc((size_t)NN * 4);
    __half*    XLh    = (__half*)alloc((size_t)NN * HCc * 2);
    __half*    XRh    = (__half*)alloc((size_t)NN * HCc * 2);
    __half*    EAc    = (__half*)alloc((size_t)EE * 4 * 2);
    float*     NLn    = (float*)alloc((size_t)NN * 4 * 4);
    float*     NRn    = (float*)alloc((size_t)NN * 4 * 4);
    float*     HA     = (float*)alloc((size_t)NN * DHc * 4);
    float*     HB     = (float*)alloc((size_t)NN * DHc * 4);

    (void)hipMemsetAsync(counts, 0, (size_t)(NN + 1) * 4, stream);
    (void)hipMemsetAsync(flag, 0, 4, stream);

    detect_kernel<<<1, 256, 0, stream>>>((const unsigned int*)eraw, 8192, flag);
    convert_count_kernel<<<(2 * EE + 255) / 256, 256, 0, stream>>>(eraw, flag, EI, counts, rnk);
    const int M = NN + 1;
    const int NBLK = (M + 255) / 256;
    scanA_kernel<<<NBLK, 256, 0, stream>>>(counts, roff, bsum, M);
    scanB_kernel<<<1, 256, 0, stream>>>(bsum, boff, NBLK);
    scanC_kernel<<<NBLK, 256, 0, stream>>>(roff, boff, M);
    fill_kernel<<<(EE + 255) / 256, 256, 0, stream>>>(EI, roff, rnk, ce);
    sortw_kernel<<<(NN + 3) / 4, 256, 0, stream>>>(roff, ce, (const float4*)ea, col, EAc);
    // degree-sorted perm via block-local counting sort (LDS atomics only)
    bhist_kernel<<<NBK, 256, 0, stream>>>(roff, gbh);
    bscan_kernel<<<1, 256, 0, stream>>>(gbh);
    bscatter_kernel<<<NBK, 256, 0, stream>>>(roff, gbh, perm);

    const int gT = (NN + 15) / 16;   // 3125 blocks
    const int gG = (NN + 7) / 8;     // 6250 blocks * 8 node-slots (2 per wave)

    // layer 0
    transform_kernel<DFi><<<gT, 128, 0, stream>>>(x, Wl0, bl0, Wr0, br0, XLh, XRh, NLn, NRn);
    gat_kernel<<<gG, 256, 0, stream>>>(XLh, XRh, NLn, NRn, roff, col, EAc, perm, We0, att0, bo0, HA);
    // layer 1
    transform_kernel<DHc><<<gT, 128, 0, stream>>>(HA, Wl, bl, Wr, br, XLh, XRh, NLn, NRn);
    gat_kernel<<<gG, 256, 0, stream>>>(XLh, XRh, NLn, NRn, roff, col, EAc, perm, We, att, bo, HB);
    // layer 2
    transform_kernel<DHc><<<gT, 128, 0, stream>>>(HB, Wl + DHc * HCc, bl + HCc, Wr + DHc * HCc, br + HCc,
                                                  XLh, XRh, NLn, NRn);
    gat_kernel<<<gG, 256, 0, stream>>>(XLh, XRh, NLn, NRn, roff, col, EAc, perm, We + DEe * HCc,
                                       att + Hh * DHc, bo + DHc, HA);
    // MLP head
    mlp_kernel<<<(NN + 63) / 64, 256, 0, stream>>>(HA, Wd1, bd1, Wd2, bd2, out);
}

// Round 18
// 394.826 us; speedup vs baseline: 1.0547x; 1.0547x over previous
//
#include <hip/hip_runtime.h>
#include <hip/hip_fp16.h>
#include <math.h>

#define NN 50000
#define EE 800000
#define DFi 8
#define DHc 32
#define Hh 4
#define HCc 128
#define DEe 4
#define DDd 256
#define DOo 4
#define NBK 196   // (NN+255)/256

// ---------------- edge-index dtype detect + convert (+count +rank fused) ----------------
__global__ void detect_kernel(const unsigned int* __restrict__ w, int nwords, int* __restrict__ flag) {
    unsigned int acc = 0;
    for (int i = 2 * threadIdx.x + 1; i < nwords; i += 512) acc |= w[i];
    if (acc) atomicOr(flag, 1);
}

__global__ void convert_count_kernel(const void* __restrict__ buf, const int* __restrict__ flag,
                                     int* __restrict__ EI, int* __restrict__ counts,
                                     int* __restrict__ rnk) {
    int i = blockIdx.x * 256 + threadIdx.x;
    if (i >= 2 * EE) return;
    int v = (*flag) ? ((const int*)buf)[i] : (int)(((const long long*)buf)[i]);
    EI[i] = v;
    if (i >= EE) rnk[i - EE] = atomicAdd(&counts[v], 1);
}

// ---------------- CSR build ----------------
__global__ void scanA_kernel(const int* __restrict__ counts, int* __restrict__ roff,
                             int* __restrict__ bsum, int M) {
    __shared__ int sd[256];
    int t = threadIdx.x;
    int idx = blockIdx.x * 256 + t;
    int v = (idx < M) ? counts[idx] : 0;
    sd[t] = v;
    __syncthreads();
    for (int off = 1; off < 256; off <<= 1) {
        int x = (t >= off) ? sd[t - off] : 0;
        __syncthreads();
        sd[t] += x;
        __syncthreads();
    }
    if (idx < M) roff[idx] = sd[t] - v;      // exclusive
    if (t == 255) bsum[blockIdx.x] = sd[255];
}

__global__ void scanB_kernel(const int* __restrict__ bsum, int* __restrict__ boff, int nb) {
    __shared__ int sd[256];
    int t = threadIdx.x;
    int v = (t < nb) ? bsum[t] : 0;
    sd[t] = v;
    __syncthreads();
    for (int off = 1; off < 256; off <<= 1) {
        int x = (t >= off) ? sd[t - off] : 0;
        __syncthreads();
        sd[t] += x;
        __syncthreads();
    }
    boff[t] = sd[t] - v;                     // exclusive
}

__global__ void scanC_kernel(int* __restrict__ roff, const int* __restrict__ boff, int M) {
    int idx = blockIdx.x * 256 + threadIdx.x;
    if (idx < M) roff[idx] += boff[idx >> 8];
}

// no atomics: rank was captured during the count pass
__global__ void fill_kernel(const int* __restrict__ EI, const int* __restrict__ roff,
                            const int* __restrict__ rnk, long long* __restrict__ ce) {
    int e = blockIdx.x * 256 + threadIdx.x;
    if (e >= EE) return;
    int d = EI[EE + e];
    int s = EI[e];
    ce[roff[d] + rnk[e]] = ((long long)e << 32) | (unsigned int)s;
}

// sort each segment by eid (deterministic) AND materialize CSR-ordered col[] + fp16 EAc[].
__global__ __launch_bounds__(256) void sortw_kernel(const int* __restrict__ roff,
                                                    long long* __restrict__ ce,
                                                    const float4* __restrict__ EA4,
                                                    int* __restrict__ col,
                                                    __half* __restrict__ EAc) {
    const int n = blockIdx.x * 4 + (threadIdx.x >> 6);
    if (n >= NN) return;
    const int lane = threadIdx.x & 63;
    const int a = roff[n];
    const int d = roff[n + 1] - a;
    if (d <= 0) return;
    if (d <= 64) {
        int srcv = 0;
        unsigned key = 0xFFFFFFFFu;
        if (lane < d) {
            long long v = ce[a + lane];
            srcv = (int)(v & 0xffffffffLL);
            unsigned eid = (unsigned)(v >> 32);
            key = (eid << 6) | (unsigned)lane;
        }
#pragma unroll
        for (int k = 2; k <= 64; k <<= 1) {
#pragma unroll
            for (int j = k >> 1; j > 0; j >>= 1) {
                unsigned o = (unsigned)__shfl_xor((int)key, j);
                bool up = ((lane & k) == 0);
                bool lower = ((lane & j) == 0);
                unsigned mn = o < key ? o : key;
                unsigned mx = o < key ? key : o;
                key = (lower == up) ? mn : mx;
            }
        }
        if (lane < d) {
            int ol = (int)(key & 63u);
            int src = __shfl(srcv, ol);
            unsigned eid = key >> 6;
            col[a + lane] = src;
            float4 at = EA4[eid];
            __half2 lo = __floats2half2_rn(at.x, at.y);
            __half2 hi = __floats2half2_rn(at.z, at.w);
            uint2 pk;
            pk.x = *reinterpret_cast<unsigned int*>(&lo);
            pk.y = *reinterpret_cast<unsigned int*>(&hi);
            reinterpret_cast<uint2*>(EAc)[a + lane] = pk;
        }
    } else if (lane == 0) {
        for (int i2 = a + 1; i2 < a + d; i2++) {
            long long kk = ce[i2];
            int j2 = i2 - 1;
            while (j2 >= a && ce[j2] > kk) { ce[j2 + 1] = ce[j2]; j2--; }
            ce[j2 + 1] = kk;
        }
        for (int k = 0; k < d; k++) {
            long long key = ce[a + k];
            int src = (int)(key & 0xffffffffLL);
            int eid = (int)(key >> 32);
            col[a + k] = src;
            float4 at = EA4[eid];
            __half2 lo = __floats2half2_rn(at.x, at.y);
            __half2 hi = __floats2half2_rn(at.z, at.w);
            uint2 pk;
            pk.x = *reinterpret_cast<unsigned int*>(&lo);
            pk.y = *reinterpret_cast<unsigned int*>(&hi);
            reinterpret_cast<uint2*>(EAc)[a + k] = pk;
        }
    }
}

// ---------------- degree-sorted node permutation: block-local counting sort (LDS only) ------
__global__ __launch_bounds__(256) void bhist_kernel(const int* __restrict__ roff, int* __restrict__ gbh) {
    __shared__ int hist[256];
    int t = threadIdx.x;
    hist[t] = 0;
    __syncthreads();
    int n = blockIdx.x * 256 + t;
    if (n < NN) {
        int d = roff[n + 1] - roff[n];
        atomicAdd(&hist[d < 255 ? d : 255], 1);
    }
    __syncthreads();
    gbh[t * NBK + blockIdx.x] = hist[t];
}

__global__ __launch_bounds__(256) void bscan_kernel(int* __restrict__ gbh) {
    __shared__ int sd[256];
    int bin = threadIdx.x;
    int s = 0;
    for (int b = 0; b < NBK; b++) { int v = gbh[bin * NBK + b]; gbh[bin * NBK + b] = s; s += v; }
    int r = 255 - bin;                 // reversed: heavy bins first (LPT)
    sd[r] = s;
    __syncthreads();
    for (int off = 1; off < 256; off <<= 1) {
        int x = (r >= off) ? sd[r - off] : 0;
        __syncthreads();
        sd[r] += x;
        __syncthreads();
    }
    int base = sd[r] - s;
    for (int b = 0; b < NBK; b++) gbh[bin * NBK + b] += base;
}

__global__ __launch_bounds__(256) void bscatter_kernel(const int* __restrict__ roff,
                                                       const int* __restrict__ gbh,
                                                       int* __restrict__ perm) {
    __shared__ int hist[256];
    int t = threadIdx.x;
    hist[t] = 0;
    __syncthreads();
    int n = blockIdx.x * 256 + t;
    if (n < NN) {
        int d = roff[n + 1] - roff[n];
        int bin = d < 255 ? d : 255;
        int lr = atomicAdd(&hist[bin], 1);
        perm[gbh[bin * NBK + blockIdx.x] + lr] = n;
    }
}

// ---------------- node transform: XLh/XRh = fp16 transforms, per-head norms (f32) ----------
template <int IN>
__global__ __launch_bounds__(128) void transform_kernel(
    const float* __restrict__ Xin, const float* __restrict__ Wl, const float* __restrict__ bl,
    const float* __restrict__ Wr, const float* __restrict__ br,
    __half* __restrict__ XLh, __half* __restrict__ XRh,
    float* __restrict__ NLn, float* __restrict__ NRn) {
    const int t = threadIdx.x;
    float wl[IN], wr[IN];
#pragma unroll
    for (int k = 0; k < IN; k++) { wl[k] = Wl[k * HCc + t]; wr[k] = Wr[k * HCc + t]; }
    const float blv = bl[t], brv = br[t];
    __shared__ float xst[16][IN];
    const int nbeg = blockIdx.x * 16;
    for (int idx = t; idx < 16 * IN; idx += 128) {
        int r = idx / IN, cc = idx % IN;
        int n = nbeg + r;
        xst[r][cc] = (n < NN) ? Xin[n * IN + cc] : 0.f;
    }
    __syncthreads();
#pragma unroll 4
    for (int r = 0; r < 16; ++r) {
        int n = nbeg + r;
        if (n >= NN) break;
        float al = blv, ar = brv;
#pragma unroll
        for (int k = 0; k < IN; k++) { float xv = xst[r][k]; al = fmaf(xv, wl[k], al); ar = fmaf(xv, wr[k], ar); }
        XLh[n * HCc + t] = __float2half(al);
        XRh[n * HCc + t] = __float2half(ar);
        float sl = al * al, sr = ar * ar;
#pragma unroll
        for (int msk = 1; msk < 32; msk <<= 1) { sl += __shfl_xor(sl, msk); sr += __shfl_xor(sr, msk); }
        if ((t & 31) == 0) { NLn[n * 4 + (t >> 5)] = sqrtf(sl); NRn[n * 4 + (t >> 5)] = sqrtf(sr); }
    }
}

__device__ inline float4 h8tof4(unsigned int a, unsigned int b) {
    __half2 p0 = *reinterpret_cast<const __half2*>(&a);
    __half2 p1 = *reinterpret_cast<const __half2*>(&b);
    float2 lo = __half22float2(p0), hi = __half22float2(p1);
    return make_float4(lo.x, lo.y, hi.x, hi.y);
}

// ---------------- fused per-node GAT layer: 4 nodes per wave, degree-sorted (LPT) ------------
// 16-lane group g = lane>>4 owns ONE node; lane c = lane&15 owns fp16 channels 8c..8c+7
// (head = c>>2). 4 edges per wave-BODY; depth-6 pipeline. Known-good R16 configuration.
__global__ __launch_bounds__(256) void gat_kernel(
    const __half* __restrict__ XLh, const __half* __restrict__ XRh,
    const float* __restrict__ NLn, const float* __restrict__ NRn,
    const int* __restrict__ roff, const int* __restrict__ col,
    const __half* __restrict__ EAc, const int* __restrict__ perm,
    const float* __restrict__ We,
    const float* __restrict__ att, const float* __restrict__ bo,
    float* __restrict__ Hout) {
    const int lane = threadIdx.x & 63;
    const int c = lane & 15;
    const int g = lane >> 4;
    const int h = c >> 2;
    const int slot = blockIdx.x * 16 + (threadIdx.x >> 6) * 4 + g;
    if (slot >= NN) return;
    const int i = perm[slot];

    const uint4*  XLu4 = reinterpret_cast<const uint4*>(XLh);
    const uint4*  XRu4 = reinterpret_cast<const uint4*>(XRh);
    const uint2*  EAu2 = reinterpret_cast<const uint2*>(EAc);
    const float4* NL4 = reinterpret_cast<const float4*>(NLn);
    const float4* We4 = reinterpret_cast<const float4*>(We);
    const float4* at4 = reinterpret_cast<const float4*>(att);
    const float4* bo4 = reinterpret_cast<const float4*>(bo);
    float4* Ho4 = reinterpret_cast<float4*>(Hout);

    const int base = roff[i];
    const int deg = roff[i + 1] - base;

    if (deg == 0) {
        if (c < 8) {
            float4 b = bo4[c];
            float4 r;
            r.x = b.x > 0.f ? b.x : 0.01f * b.x;
            r.y = b.y > 0.f ? b.y : 0.01f * b.y;
            r.z = b.z > 0.f ? b.z : 0.01f * b.z;
            r.w = b.w > 0.f ? b.w : 0.01f * b.w;
            Ho4[i * 8 + c] = r;
        }
        return;
    }

    const float4 w0l = We4[2 * c],      w0h = We4[2 * c + 1];
    const float4 w1l = We4[32 + 2 * c], w1h = We4[32 + 2 * c + 1];
    const float4 w2l = We4[64 + 2 * c], w2h = We4[64 + 2 * c + 1];
    const float4 w3l = We4[96 + 2 * c], w3h = We4[96 + 2 * c + 1];
    const float4 atl = at4[2 * c],      ath = at4[2 * c + 1];

    uint4 xiu = XRu4[i * 16 + c];
    const float4 xil = h8tof4(xiu.x, xiu.y), xih = h8tof4(xiu.z, xiu.w);
    float srun = 0.f;
    float4 accl = make_float4(0.f, 0.f, 0.f, 0.f);
    float4 acch = make_float4(0.f, 0.f, 0.f, 0.f);

#define ISSUE(X_, E_, K)                                                          \
    {                                                                             \
        int kc = ((K) < deg) ? (K) : 0;                                           \
        int jx = col[base + kc];                                                  \
        X_ = XLu4[jx * 16 + c];                                                   \
        E_ = EAu2[base + kc];                                                     \
    }
    uint4 xA, xB, xC, xD, xE, xF;
    uint2 eA, eB, eC, eD, eE, eF;
    ISSUE(xA, eA, 0); ISSUE(xB, eB, 1); ISSUE(xC, eC, 2);
    ISSUE(xD, eD, 3); ISSUE(xE, eE, 4); ISSUE(xF, eF, 5);

    // phase 1: Lipschitz max of in-neighbor norms (strided over 16 lanes; norms >= 0)
    float4 mx = make_float4(0.f, 0.f, 0.f, 0.f);
    for (int k = c; k < deg; k += 16) {
        int j = col[base + k];
        float4 nj = NL4[j];
        mx.x = fmaxf(mx.x, nj.x); mx.y = fmaxf(mx.y, nj.y);
        mx.z = fmaxf(mx.z, nj.z); mx.w = fmaxf(mx.w, nj.w);
    }
#pragma unroll
    for (int msk = 1; msk < 16; msk <<= 1) {
        mx.x = fmaxf(mx.x, __shfl_xor(mx.x, msk));
        mx.y = fmaxf(mx.y, __shfl_xor(mx.y, msk));
        mx.z = fmaxf(mx.z, __shfl_xor(mx.z, msk));
        mx.w = fmaxf(mx.w, __shfl_xor(mx.w, msk));
    }
    float mxh = (h == 0) ? mx.x : (h == 1) ? mx.y : (h == 2) ? mx.z : mx.w;
    const float invD = 1.0f / (4.0f * (NRn[i * 4 + h] + mxh) + 1e-12f);

#define BODY(X_, E_, K)                                                           \
    {                                                                             \
        float4 a4 = h8tof4((E_).x, (E_).y);                                       \
        float4 xjl = h8tof4((X_).x, (X_).y);                                      \
        float4 xjh = h8tof4((X_).z, (X_).w);                                      \
        float e0 = a4.x * w0l.x; e0 = fmaf(a4.y, w1l.x, e0);                      \
        e0 = fmaf(a4.z, w2l.x, e0); e0 = fmaf(a4.w, w3l.x, e0);                   \
        float e1 = a4.x * w0l.y; e1 = fmaf(a4.y, w1l.y, e1);                      \
        e1 = fmaf(a4.z, w2l.y, e1); e1 = fmaf(a4.w, w3l.y, e1);                   \
        float e2 = a4.x * w0l.z; e2 = fmaf(a4.y, w1l.z, e2);                      \
        e2 = fmaf(a4.z, w2l.z, e2); e2 = fmaf(a4.w, w3l.z, e2);                   \
        float e3 = a4.x * w0l.w; e3 = fmaf(a4.y, w1l.w, e3);                      \
        e3 = fmaf(a4.z, w2l.w, e3); e3 = fmaf(a4.w, w3l.w, e3);                   \
        float e4 = a4.x * w0h.x; e4 = fmaf(a4.y, w1h.x, e4);                      \
        e4 = fmaf(a4.z, w2h.x, e4); e4 = fmaf(a4.w, w3h.x, e4);                   \
        float e5 = a4.x * w0h.y; e5 = fmaf(a4.y, w1h.y, e5);                      \
        e5 = fmaf(a4.z, w2h.y, e5); e5 = fmaf(a4.w, w3h.y, e5);                   \
        float e6 = a4.x * w0h.z; e6 = fmaf(a4.y, w1h.z, e6);                      \
        e6 = fmaf(a4.z, w2h.z, e6); e6 = fmaf(a4.w, w3h.z, e6);                   \
        float e7 = a4.x * w0h.w; e7 = fmaf(a4.y, w1h.w, e7);                      \
        e7 = fmaf(a4.z, w2h.w, e7); e7 = fmaf(a4.w, w3h.w, e7);                   \
        float s0 = xil.x + xjl.x + e0; s0 = s0 > 0.f ? s0 : 0.2f * s0;            \
        float s1 = xil.y + xjl.y + e1; s1 = s1 > 0.f ? s1 : 0.2f * s1;            \
        float s2 = xil.z + xjl.z + e2; s2 = s2 > 0.f ? s2 : 0.2f * s2;            \
        float s3 = xil.w + xjl.w + e3; s3 = s3 > 0.f ? s3 : 0.2f * s3;            \
        float s4 = xih.x + xjh.x + e4; s4 = s4 > 0.f ? s4 : 0.2f * s4;            \
        float s5 = xih.y + xjh.y + e5; s5 = s5 > 0.f ? s5 : 0.2f * s5;            \
        float s6 = xih.z + xjh.z + e6; s6 = s6 > 0.f ? s6 : 0.2f * s6;            \
        float s7 = xih.w + xjh.w + e7; s7 = s7 > 0.f ? s7 : 0.2f * s7;            \
        float pp = s0 * atl.x; pp = fmaf(s1, atl.y, pp);                          \
        pp = fmaf(s2, atl.z, pp); pp = fmaf(s3, atl.w, pp);                       \
        pp = fmaf(s4, ath.x, pp); pp = fmaf(s5, ath.y, pp);                       \
        pp = fmaf(s6, ath.z, pp); pp = fmaf(s7, ath.w, pp);                       \
        pp += __shfl_xor(pp, 1); pp += __shfl_xor(pp, 2);                         \
        float z = __expf(fminf(pp * invD, 60.f));                                 \
        z = ((K) < deg) ? z : 0.f;                                                \
        srun += z;                                                                \
        accl.x = fmaf(z, xjl.x, accl.x);                                          \
        accl.y = fmaf(z, xjl.y, accl.y);                                          \
        accl.z = fmaf(z, xjl.z, accl.z);                                          \
        accl.w = fmaf(z, xjl.w, accl.w);                                          \
        acch.x = fmaf(z, xjh.x, acch.x);                                          \
        acch.y = fmaf(z, xjh.y, acch.y);                                          \
        acch.z = fmaf(z, xjh.z, acch.z);                                          \
        acch.w = fmaf(z, xjh.w, acch.w);                                          \
    }

    for (int k = 0; k < deg; k += 3) {
        uint4 nxD, nxE, nxF;
        uint2 neD, neE, neF;
        ISSUE(nxD, neD, k + 6);
        ISSUE(nxE, neE, k + 7);
        ISSUE(nxF, neF, k + 8);
        BODY(xA, eA, k);
        if (k + 1 < deg) BODY(xB, eB, k + 1);
        if (k + 2 < deg) BODY(xC, eC, k + 2);
        xA = xD; eA = eD; xB = xE; eB = eE; xC = xF; eC = eF;
        xD = nxD; eD = neD; xE = nxE; eE = neE; xF = nxF; eF = neF;
    }
#undef BODY
#undef ISSUE

    float inv = 1.0f / (srun + 1e-16f);
    float a0 = accl.x * inv, a1 = accl.y * inv, a2 = accl.z * inv, a3 = accl.w * inv;
    float a4_ = acch.x * inv, a5 = acch.y * inv, a6 = acch.z * inv, a7 = acch.w * inv;
    a0 += __shfl_xor(a0, 4); a0 += __shfl_xor(a0, 8);
    a1 += __shfl_xor(a1, 4); a1 += __shfl_xor(a1, 8);
    a2 += __shfl_xor(a2, 4); a2 += __shfl_xor(a2, 8);
    a3 += __shfl_xor(a3, 4); a3 += __shfl_xor(a3, 8);
    a4_ += __shfl_xor(a4_, 4); a4_ += __shfl_xor(a4_, 8);
    a5 += __shfl_xor(a5, 4); a5 += __shfl_xor(a5, 8);
    a6 += __shfl_xor(a6, 4); a6 += __shfl_xor(a6, 8);
    a7 += __shfl_xor(a7, 4); a7 += __shfl_xor(a7, 8);

    if (c < 4) {
        float4 bl_ = bo4[2 * c], bh_ = bo4[2 * c + 1];
        float4 rl, rh;
        rl.x = fmaf(0.25f, a0, bl_.x); rl.x = rl.x > 0.f ? rl.x : 0.01f * rl.x;
        rl.y = fmaf(0.25f, a1, bl_.y); rl.y = rl.y > 0.f ? rl.y : 0.01f * rl.y;
        rl.z = fmaf(0.25f, a2, bl_.z); rl.z = rl.z > 0.f ? rl.z : 0.01f * rl.z;
        rl.w = fmaf(0.25f, a3, bl_.w); rl.w = rl.w > 0.f ? rl.w : 0.01f * rl.w;
        rh.x = fmaf(0.25f, a4_, bh_.x); rh.x = rh.x > 0.f ? rh.x : 0.01f * rh.x;
        rh.y = fmaf(0.25f, a5, bh_.y); rh.y = rh.y > 0.f ? rh.y : 0.01f * rh.y;
        rh.z = fmaf(0.25f, a6, bh_.z); rh.z = rh.z > 0.f ? rh.z : 0.01f * rh.z;
        rh.w = fmaf(0.25f, a7, bh_.w); rh.w = rh.w > 0.f ? rh.w : 0.01f * rh.w;
        Ho4[i * 8 + 2 * c] = rl;
        Ho4[i * 8 + 2 * c + 1] = rh;
    }
}

// ---------------- MLP head ----------------
__global__ __launch_bounds__(256) void mlp_kernel(
    const float* __restrict__ Hin, const float* __restrict__ Wd1, const float* __restrict__ bd1,
    const float* __restrict__ Wd2, const float* __restrict__ bd2, float* __restrict__ out) {
    const int lane = threadIdx.x & 63;
    const int chunk = __builtin_amdgcn_readfirstlane(threadIdx.x >> 6);
    const int nb = blockIdx.x * 64;
    int node = nb + lane;
    int nclamp = node < NN ? node : NN - 1;

    float h[32];
    const float4* H4 = reinterpret_cast<const float4*>(Hin);
#pragma unroll
    for (int r = 0; r < 8; ++r) {
        float4 t = H4[nclamp * 8 + r];
        h[4 * r] = t.x; h[4 * r + 1] = t.y; h[4 * r + 2] = t.z; h[4 * r + 3] = t.w;
    }

    float o0 = 0.f, o1 = 0.f, o2 = 0.f, o3 = 0.f;
    const int dbase = chunk * 64;
    for (int t = 0; t < 4; ++t) {
        float acc[16];
#pragma unroll
        for (int j = 0; j < 16; ++j) acc[j] = bd1[dbase + t * 16 + j];
#pragma unroll 8
        for (int k = 0; k < 32; ++k) {
            const float* wr = Wd1 + k * DDd + dbase + t * 16;
#pragma unroll
            for (int j = 0; j < 16; ++j) acc[j] = fmaf(h[k], wr[j], acc[j]);
        }
#pragma unroll
        for (int j = 0; j < 16; ++j) {
            float hd = acc[j];
            hd = hd > 0.f ? hd : 0.01f * hd;
            int d = dbase + t * 16 + j;
            o0 = fmaf(hd, Wd2[d * 4 + 0], o0);
            o1 = fmaf(hd, Wd2[d * 4 + 1], o1);
            o2 = fmaf(hd, Wd2[d * 4 + 2], o2);
            o3 = fmaf(hd, Wd2[d * 4 + 3], o3);
        }
    }

    __shared__ float4 red[4][64];
    red[chunk][lane] = make_float4(o0, o1, o2, o3);
    __syncthreads();
    if (threadIdx.x < 64 && nb + (int)threadIdx.x < NN) {
        float4 r0 = red[0][threadIdx.x], r1 = red[1][threadIdx.x];
        float4 r2 = red[2][threadIdx.x], r3 = red[3][threadIdx.x];
        float4 o;
        o.x = r0.x + r1.x + r2.x + r3.x + bd2[0];
        o.y = r0.y + r1.y + r2.y + r3.y + bd2[1];
        o.z = r0.z + r1.z + r2.z + r3.z + bd2[2];
        o.w = r0.w + r1.w + r2.w + r3.w + bd2[3];
        reinterpret_cast<float4*>(out)[nb + threadIdx.x] = o;
    }
}

extern "C" void kernel_launch(void* const* d_in, const int* in_sizes, int n_in,
                              void* d_out, int out_size, void* d_ws, size_t ws_size,
                              hipStream_t stream) {
    const float* x    = (const float*)d_in[0];
    const void*  eraw = d_in[1];
    const float* ea   = (const float*)d_in[2];
    const float* Wl0  = (const float*)d_in[3];
    const float* bl0  = (const float*)d_in[4];
    const float* Wr0  = (const float*)d_in[5];
    const float* br0  = (const float*)d_in[6];
    const float* We0  = (const float*)d_in[7];
    const float* att0 = (const float*)d_in[8];
    const float* bo0  = (const float*)d_in[9];
    const float* Wl   = (const float*)d_in[10];
    const float* bl   = (const float*)d_in[11];
    const float* Wr   = (const float*)d_in[12];
    const float* br   = (const float*)d_in[13];
    const float* We   = (const float*)d_in[14];
    const float* att  = (const float*)d_in[15];
    const float* bo   = (const float*)d_in[16];
    const float* Wd1  = (const float*)d_in[17];
    const float* bd1  = (const float*)d_in[18];
    const float* Wd2  = (const float*)d_in[19];
    const float* bd2  = (const float*)d_in[20];
    float* out = (float*)d_out;

    char* p = (char*)d_ws;
    auto alloc = [&](size_t bytes) { void* r = (void*)p; p += (bytes + 255) & ~(size_t)255; return r; };
    int*       EI     = (int*)alloc((size_t)2 * EE * 4);
    int*       counts = (int*)alloc((size_t)(NN + 1) * 4);
    int*       roff   = (int*)alloc((size_t)(NN + 1) * 4);
    int*       bsum   = (int*)alloc(256 * 4);
    int*       boff   = (int*)alloc(256 * 4);
    int*       rnk    = (int*)alloc((size_t)EE * 4);
    long long* ce     = (long long*)alloc((size_t)EE * 8);
    int*       col    = (int*)alloc((size_t)EE * 4);
    int*       flag   = (int*)alloc(256);
    int*       gbh    = (int*)alloc((size_t)256 * NBK * 4);
    int*       perm   = (int*)alloc((size_t)NN * 4);
    __half*    XLh    = (__half*)alloc((size_t)NN * HCc * 2);
    __half*    XRh    = (__half*)alloc((size_t)NN * HCc * 2);
    __half*    EAc    = (__half*)alloc((size_t)EE * 4 * 2);
    float*     NLn    = (float*)alloc((size_t)NN * 4 * 4);
    float*     NRn    = (float*)alloc((size_t)NN * 4 * 4);
    float*     HA     = (float*)alloc((size_t)NN * DHc * 4);
    float*     HB     = (float*)alloc((size_t)NN * DHc * 4);

    (void)hipMemsetAsync(counts, 0, (size_t)(NN + 1) * 4, stream);
    (void)hipMemsetAsync(flag, 0, 4, stream);

    detect_kernel<<<1, 256, 0, stream>>>((const unsigned int*)eraw, 8192, flag);
    convert_count_kernel<<<(2 * EE + 255) / 256, 256, 0, stream>>>(eraw, flag, EI, counts, rnk);
    const int M = NN + 1;
    const int NBLK = (M + 255) / 256;
    scanA_kernel<<<NBLK, 256, 0, stream>>>(counts, roff, bsum, M);
    scanB_kernel<<<1, 256, 0, stream>>>(bsum, boff, NBLK);
    scanC_kernel<<<NBLK, 256, 0, stream>>>(roff, boff, M);
    fill_kernel<<<(EE + 255) / 256, 256, 0, stream>>>(EI, roff, rnk, ce);
    sortw_kernel<<<(NN + 3) / 4, 256, 0, stream>>>(roff, ce, (const float4*)ea, col, EAc);
    // degree-sorted perm via block-local counting sort (LDS atomics only)
    bhist_kernel<<<NBK, 256, 0, stream>>>(roff, gbh);
    bscan_kernel<<<1, 256, 0, stream>>>(gbh);
    bscatter_kernel<<<NBK, 256, 0, stream>>>(roff, gbh, perm);

    const int gT = (NN + 15) / 16;   // 3125 blocks
    const int gG = (NN + 15) / 16;   // 50000 node slots, 1 per 16-lane group

    // layer 0
    transform_kernel<DFi><<<gT, 128, 0, stream>>>(x, Wl0, bl0, Wr0, br0, XLh, XRh, NLn, NRn);
    gat_kernel<<<gG, 256, 0, stream>>>(XLh, XRh, NLn, NRn, roff, col, EAc, perm, We0, att0, bo0, HA);
    // layer 1
    transform_kernel<DHc><<<gT, 128, 0, stream>>>(HA, Wl, bl, Wr, br, XLh, XRh, NLn, NRn);
    gat_kernel<<<gG, 256, 0, stream>>>(XLh, XRh, NLn, NRn, roff, col, EAc, perm, We, att, bo, HB);
    // layer 2
    transform_kernel<DHc><<<gT, 128, 0, stream>>>(HB, Wl + DHc * HCc, bl + HCc, Wr + DHc * HCc, br + HCc,
                                                  XLh, XRh, NLn, NRn);
    gat_kernel<<<gG, 256, 0, stream>>>(XLh, XRh, NLn, NRn, roff, col, EAc, perm, We + DEe * HCc,
                                       att + Hh * DHc, bo + DHc, HA);
    // MLP head
    mlp_kernel<<<(NN + 63) / 64, 256, 0, stream>>>(HA, Wd1, bd1, Wd2, bd2, out);
}